// Round 3
// baseline (163.851 us; speedup 1.0000x reference)
//
#include <hip/hip_runtime.h>
#include <math.h>

#define N_NODES 50000
#define S_NEIB 32
#define D_IN 256
#define D_OUT 128
#define ALPHA 0.2f

typedef __attribute__((ext_vector_type(8))) short bf16x8;   // 8 bf16 = 4 VGPRs
typedef __attribute__((ext_vector_type(4))) float f32x4;    // MFMA C/D

__device__ __forceinline__ float elu_f(float v) {
    return v > 0.f ? v : (expf(v) - 1.f);
}

// fp32 -> bf16 round-to-nearest-even
__device__ __forceinline__ unsigned short f2bf(float f) {
    unsigned u = __builtin_bit_cast(unsigned, f);
    u += 0x7fffu + ((u >> 16) & 1u);
    return (unsigned short)(u >> 16);
}

// Kernel 0: pack W (256x128 fp32, row-major) into bf16 MFMA B-fragment order:
// Wp[((c*32 + kb)*16 + t)*8 + j] = bf16(W[kb*8+j][c*16+t]),  c=n>>4, kb=k>>3.
// Consumer reads one coalesced 16B/lane dwordx4 per fragment.
__global__ __launch_bounds__(256) void pack_w_kernel(
    const float* __restrict__ W, unsigned short* __restrict__ Wp)
{
    int tid = blockIdx.x * 256 + threadIdx.x;        // 0..32767
    int j  = tid & 7;
    int t  = (tid >> 3) & 15;
    int kb = (tid >> 7) & 31;
    int c  = tid >> 12;
    Wp[tid] = f2bf(W[(kb * 8 + j) * D_OUT + c * 16 + t]);
}

// Kernel 1 (bf16 MFMA): xwb = bf16(x@W); s_self/s_neib = xw@a halves;
// out[:, :128] = elu(xw). 64 rows/block, 4 waves, wave owns a 32-col slice.
__global__ __launch_bounds__(256) void gemm_score_kernel(
    const float* __restrict__ x, const unsigned short* __restrict__ Wp,
    const float* __restrict__ a, unsigned short* __restrict__ xwb,
    float* __restrict__ s_self, float* __restrict__ s_neib,
    float* __restrict__ out)
{
    __shared__ unsigned short xs[64 * 264];  // 33 KB bf16 x-tile (stride 264: 2-way, free)
    __shared__ float ps[2][4][64];

    const int tid  = threadIdx.x;
    const int lane = tid & 63;
    const int wave = tid >> 6;
    const int q    = lane >> 4;     // quad 0..3
    const int t    = lane & 15;
    const int colW = wave * 32;
    const int r0   = blockIdx.x * 64;

    // stage x tile 64x256 fp32 -> bf16 LDS
    for (int i = 0; i < 16; ++i) {
        int f4  = i * 256 + tid;
        int row = f4 >> 6;
        int c4  = (f4 & 63) << 2;
        float4 v = make_float4(0.f, 0.f, 0.f, 0.f);
        if (r0 + row < N_NODES)
            v = *(const float4*)(x + (size_t)(r0 + row) * D_IN + c4);
        ushort4 b;
        b.x = f2bf(v.x); b.y = f2bf(v.y); b.z = f2bf(v.z); b.w = f2bf(v.w);
        *(ushort4*)&xs[row * 264 + c4] = b;
    }
    __syncthreads();

    const bf16x8* Wp8 = (const bf16x8*)Wp;   // fragment-granular view

    f32x4 acc[4][2];
    #pragma unroll
    for (int mt = 0; mt < 4; ++mt)
        #pragma unroll
        for (int nt = 0; nt < 2; ++nt)
            acc[mt][nt] = (f32x4){0.f, 0.f, 0.f, 0.f};

    #pragma unroll
    for (int kc = 0; kc < 8; ++kc) {
        const int k0 = kc * 32 + q * 8;
        bf16x8 afrag[4];
        #pragma unroll
        for (int mt = 0; mt < 4; ++mt)
            afrag[mt] = *(const bf16x8*)&xs[(mt * 16 + t) * 264 + k0];
        bf16x8 bfrag[2];
        #pragma unroll
        for (int nt = 0; nt < 2; ++nt)
            bfrag[nt] = Wp8[((wave * 2 + nt) * 32 + kc * 4 + q) * 16 + t];
        #pragma unroll
        for (int mt = 0; mt < 4; ++mt)
            #pragma unroll
            for (int nt = 0; nt < 2; ++nt)
                acc[mt][nt] = __builtin_amdgcn_mfma_f32_16x16x32_bf16(
                    afrag[mt], bfrag[nt], acc[mt][nt], 0, 0, 0);
    }

    // score partials: lane holds D[row=mt*16+q*4+r][col=colW+nt*16+t]
    const float as0 = a[colW + t],         as1 = a[colW + 16 + t];
    const float an0 = a[D_OUT + colW + t], an1 = a[D_OUT + colW + 16 + t];
    #pragma unroll
    for (int mt = 0; mt < 4; ++mt) {
        #pragma unroll
        for (int r = 0; r < 4; ++r) {
            float vs = acc[mt][0][r] * as0 + acc[mt][1][r] * as1;
            float vn = acc[mt][0][r] * an0 + acc[mt][1][r] * an1;
            #pragma unroll
            for (int d = 8; d >= 1; d >>= 1) {
                vs += __shfl_xor(vs, d);
                vn += __shfl_xor(vn, d);
            }
            if (t == 0) {
                int row = mt * 16 + q * 4 + r;
                ps[0][wave][row] = vs;
                ps[1][wave][row] = vn;
            }
        }
    }
    __syncthreads();
    if (tid < 64 && r0 + tid < N_NODES) {
        s_self[r0 + tid] = ps[0][0][tid] + ps[0][1][tid] + ps[0][2][tid] + ps[0][3][tid];
        s_neib[r0 + tid] = ps[1][0][tid] + ps[1][1][tid] + ps[1][2][tid] + ps[1][3][tid];
    }

    // stores: 16-lane 64B segments, 4 rows in flight
    #pragma unroll
    for (int mt = 0; mt < 4; ++mt) {
        #pragma unroll
        for (int r = 0; r < 4; ++r) {
            int g = r0 + mt * 16 + q * 4 + r;
            if (g < N_NODES) {
                #pragma unroll
                for (int nt = 0; nt < 2; ++nt) {
                    int col = colW + nt * 16 + t;
                    float v = acc[mt][nt][r];
                    xwb[(size_t)g * D_OUT + col] = f2bf(v);
                    out[(size_t)g * (2 * D_OUT) + col] = elu_f(v);
                }
            }
        }
    }
}

// Kernel 2: per-node softmax attention + aggregate over bf16 xw table.
// One wave/node; 2 edges per wave-load: lanes 0-31 even edge, 32-63 odd edge,
// 8 B/lane (4 bf16 cols) -> 256 B/row transactions, half the loads & shfls/edge.
__global__ __launch_bounds__(256, 4) void aggregate_kernel(
    const int* __restrict__ neibs, const unsigned short* __restrict__ xwb,
    const float* __restrict__ s_self, const float* __restrict__ s_neib,
    float* __restrict__ out)
{
    const int lane = threadIdx.x & 63;
    const int wave = threadIdx.x >> 6;
    const int n = blockIdx.x * 4 + wave;
    if (n >= N_NODES) return;

    const int half = lane >> 5;     // 0: even edges, 1: odd edges
    const int hl   = lane & 31;     // owns cols 4*hl .. 4*hl+3

    int   idx = 0;
    float e   = -1e30f;
    if (lane < 32) {
        idx = neibs[n * S_NEIB + lane];
        e = s_self[n] + s_neib[idx];
        e = e > 0.f ? e : ALPHA * e;            // LeakyReLU
    }
    float m = e;
    #pragma unroll
    for (int d = 16; d >= 1; d >>= 1) m = fmaxf(m, __shfl_xor(m, d));
    float p = (lane < 32) ? __expf(e - m) : 0.f;
    float ssum = p;
    #pragma unroll
    for (int d = 16; d >= 1; d >>= 1) ssum += __shfl_xor(ssum, d);
    float att = p / ssum;

    float a0 = 0.f, a1 = 0.f, a2 = 0.f, a3 = 0.f;
    #pragma unroll
    for (int s2 = 0; s2 < 16; ++s2) {
        int   s = s2 * 2 + half;
        int   j = __shfl(idx, s);
        float w = __shfl(att, s);
        uint2 v = *(const uint2*)(xwb + (size_t)j * D_OUT + 4 * hl);
        float f0 = __builtin_bit_cast(float, v.x << 16);
        float f1 = __builtin_bit_cast(float, v.x & 0xffff0000u);
        float f2 = __builtin_bit_cast(float, v.y << 16);
        float f3 = __builtin_bit_cast(float, v.y & 0xffff0000u);
        a0 = fmaf(w, f0, a0);
        a1 = fmaf(w, f1, a1);
        a2 = fmaf(w, f2, a2);
        a3 = fmaf(w, f3, a3);
    }
    // combine even/odd halves: lane l + lane l^32 hold the same 4 cols
    a0 += __shfl_xor(a0, 32);
    a1 += __shfl_xor(a1, 32);
    a2 += __shfl_xor(a2, 32);
    a3 += __shfl_xor(a3, 32);

    if (half == 0) {
        float4 o;
        o.x = elu_f(a0);
        o.y = elu_f(a1);
        o.z = elu_f(a2);
        o.w = elu_f(a3);
        *(float4*)(out + (size_t)n * (2 * D_OUT) + D_OUT + 4 * hl) = o;
    }
}

extern "C" void kernel_launch(void* const* d_in, const int* in_sizes, int n_in,
                              void* d_out, int out_size, void* d_ws, size_t ws_size,
                              hipStream_t stream) {
    const float* x     = (const float*)d_in[0];
    const int*   neibs = (const int*)  d_in[1];
    const float* W     = (const float*)d_in[2];
    const float* a     = (const float*)d_in[3];
    float* out = (float*)d_out;

    unsigned short* xwb = (unsigned short*)d_ws;              // N*128 bf16 = 12.8 MB
    float* s_self = (float*)(xwb + (size_t)N_NODES * D_OUT);  // N floats
    float* s_neib = s_self + N_NODES;                         // N floats
    unsigned short* Wp = (unsigned short*)(s_neib + N_NODES); // 256*128 bf16 = 64 KB

    pack_w_kernel<<<128, 256, 0, stream>>>(W, Wp);
    gemm_score_kernel<<<(N_NODES + 63) / 64, 256, 0, stream>>>(
        x, Wp, a, xwb, s_self, s_neib, out);
    aggregate_kernel<<<(N_NODES + 3) / 4, 256, 0, stream>>>(
        neibs, xwb, s_self, s_neib, out);
}

// Round 4
// 163.431 us; speedup vs baseline: 1.0026x; 1.0026x over previous
//
#include <hip/hip_runtime.h>
#include <math.h>

#define N_NODES 50000
#define S_NEIB 32
#define D_IN 256
#define D_OUT 128
#define ALPHA 0.2f

typedef __attribute__((ext_vector_type(8))) short bf16x8;   // 8 bf16 = 4 VGPRs
typedef __attribute__((ext_vector_type(4))) float f32x4;    // MFMA C/D

__device__ __forceinline__ float elu_f(float v) {
    return v > 0.f ? v : (expf(v) - 1.f);
}

// fp32 -> bf16 round-to-nearest-even
__device__ __forceinline__ unsigned short f2bf(float f) {
    unsigned u = __builtin_bit_cast(unsigned, f);
    u += 0x7fffu + ((u >> 16) & 1u);
    return (unsigned short)(u >> 16);
}

__device__ __forceinline__ float bflo(unsigned v) {
    return __builtin_bit_cast(float, v << 16);
}
__device__ __forceinline__ float bfhi(unsigned v) {
    return __builtin_bit_cast(float, v & 0xffff0000u);
}

// Kernel 0: pack W (256x128 fp32, row-major) into bf16 MFMA B-fragment order:
// Wp[((c*32 + kb)*16 + t)*8 + j] = bf16(W[kb*8+j][c*16+t]),  c=n>>4, kb=k>>3.
__global__ __launch_bounds__(256) void pack_w_kernel(
    const float* __restrict__ W, unsigned short* __restrict__ Wp)
{
    int tid = blockIdx.x * 256 + threadIdx.x;        // 0..32767
    int j  = tid & 7;
    int t  = (tid >> 3) & 15;
    int kb = (tid >> 7) & 31;
    int c  = tid >> 12;
    Wp[tid] = f2bf(W[(kb * 8 + j) * D_OUT + c * 16 + t]);
}

// Kernel 1 (bf16 MFMA): xwb = bf16(x@W); s_self/s_neib = xw@a halves;
// out[:, :128] = elu(xw). 64 rows/block, 4 waves, wave owns a 32-col slice.
__global__ __launch_bounds__(256) void gemm_score_kernel(
    const float* __restrict__ x, const unsigned short* __restrict__ Wp,
    const float* __restrict__ a, unsigned short* __restrict__ xwb,
    float* __restrict__ s_self, float* __restrict__ s_neib,
    float* __restrict__ out)
{
    __shared__ unsigned short xs[64 * 264];  // 33 KB bf16 x-tile (stride 264: 2-way, free)
    __shared__ float ps[2][4][64];

    const int tid  = threadIdx.x;
    const int lane = tid & 63;
    const int wave = tid >> 6;
    const int q    = lane >> 4;     // quad 0..3
    const int t    = lane & 15;
    const int colW = wave * 32;
    const int r0   = blockIdx.x * 64;

    // stage x tile 64x256 fp32 -> bf16 LDS
    for (int i = 0; i < 16; ++i) {
        int f4  = i * 256 + tid;
        int row = f4 >> 6;
        int c4  = (f4 & 63) << 2;
        float4 v = make_float4(0.f, 0.f, 0.f, 0.f);
        if (r0 + row < N_NODES)
            v = *(const float4*)(x + (size_t)(r0 + row) * D_IN + c4);
        ushort4 b;
        b.x = f2bf(v.x); b.y = f2bf(v.y); b.z = f2bf(v.z); b.w = f2bf(v.w);
        *(ushort4*)&xs[row * 264 + c4] = b;
    }
    __syncthreads();

    const bf16x8* Wp8 = (const bf16x8*)Wp;   // fragment-granular view

    f32x4 acc[4][2];
    #pragma unroll
    for (int mt = 0; mt < 4; ++mt)
        #pragma unroll
        for (int nt = 0; nt < 2; ++nt)
            acc[mt][nt] = (f32x4){0.f, 0.f, 0.f, 0.f};

    #pragma unroll
    for (int kc = 0; kc < 8; ++kc) {
        const int k0 = kc * 32 + q * 8;
        bf16x8 afrag[4];
        #pragma unroll
        for (int mt = 0; mt < 4; ++mt)
            afrag[mt] = *(const bf16x8*)&xs[(mt * 16 + t) * 264 + k0];
        bf16x8 bfrag[2];
        #pragma unroll
        for (int nt = 0; nt < 2; ++nt)
            bfrag[nt] = Wp8[((wave * 2 + nt) * 32 + kc * 4 + q) * 16 + t];
        #pragma unroll
        for (int mt = 0; mt < 4; ++mt)
            #pragma unroll
            for (int nt = 0; nt < 2; ++nt)
                acc[mt][nt] = __builtin_amdgcn_mfma_f32_16x16x32_bf16(
                    afrag[mt], bfrag[nt], acc[mt][nt], 0, 0, 0);
    }

    // score partials: lane holds D[row=mt*16+q*4+r][col=colW+nt*16+t]
    const float as0 = a[colW + t],         as1 = a[colW + 16 + t];
    const float an0 = a[D_OUT + colW + t], an1 = a[D_OUT + colW + 16 + t];
    #pragma unroll
    for (int mt = 0; mt < 4; ++mt) {
        #pragma unroll
        for (int r = 0; r < 4; ++r) {
            float vs = acc[mt][0][r] * as0 + acc[mt][1][r] * as1;
            float vn = acc[mt][0][r] * an0 + acc[mt][1][r] * an1;
            #pragma unroll
            for (int d = 8; d >= 1; d >>= 1) {
                vs += __shfl_xor(vs, d);
                vn += __shfl_xor(vn, d);
            }
            if (t == 0) {
                int row = mt * 16 + q * 4 + r;
                ps[0][wave][row] = vs;
                ps[1][wave][row] = vn;
            }
        }
    }
    __syncthreads();
    if (tid < 64 && r0 + tid < N_NODES) {
        s_self[r0 + tid] = ps[0][0][tid] + ps[0][1][tid] + ps[0][2][tid] + ps[0][3][tid];
        s_neib[r0 + tid] = ps[1][0][tid] + ps[1][1][tid] + ps[1][2][tid] + ps[1][3][tid];
    }

    // stores: 16-lane 64B segments, 4 rows in flight
    #pragma unroll
    for (int mt = 0; mt < 4; ++mt) {
        #pragma unroll
        for (int r = 0; r < 4; ++r) {
            int g = r0 + mt * 16 + q * 4 + r;
            if (g < N_NODES) {
                #pragma unroll
                for (int nt = 0; nt < 2; ++nt) {
                    int col = colW + nt * 16 + t;
                    float v = acc[mt][nt][r];
                    xwb[(size_t)g * D_OUT + col] = f2bf(v);
                    out[(size_t)g * (2 * D_OUT) + col] = elu_f(v);
                }
            }
        }
    }
}

// Kernel 2: softmax attention + aggregate over bf16 xw table.
// 2 nodes per wave: lanes 0-31 = node n0, lanes 32-63 = node n0+1.
// Explicit 8-deep double-buffered prefetch forces 8-16 gathers in flight/wave
// (round-3 showed VGPR=32 -> compiler serialized to ~2-3 outstanding; this
// kernel is latency-bound, not issue-bound: halving instrs was a no-op).
__global__ __launch_bounds__(256, 4) void aggregate_kernel(
    const int* __restrict__ neibs, const unsigned short* __restrict__ xwb,
    const float* __restrict__ s_self, const float* __restrict__ s_neib,
    float* __restrict__ out)
{
    const int lane  = threadIdx.x & 63;
    const int wavei = threadIdx.x >> 6;
    const int n0 = (blockIdx.x * 4 + wavei) * 2;
    if (n0 >= N_NODES) return;

    const int half = lane >> 5;         // which node of the pair
    const int hl   = lane & 31;         // owns cols 4*hl .. 4*hl+3 of its node
    const int node = n0 + half;         // N even -> always < N_NODES
    const int srcb = lane & 32;         // shfl source base for this half

    // lanes 0..63 cover both nodes' 32 edges contiguously
    int   idx = neibs[n0 * S_NEIB + lane];
    float e   = s_self[node] + s_neib[idx];
    e = e > 0.f ? e : ALPHA * e;        // LeakyReLU

    // softmax within each 32-lane half (xor d<=16 stays inside the half)
    float m = e;
    #pragma unroll
    for (int d = 16; d >= 1; d >>= 1) m = fmaxf(m, __shfl_xor(m, d));
    float p = __expf(e - m);
    float ssum = p;
    #pragma unroll
    for (int d = 16; d >= 1; d >>= 1) ssum += __shfl_xor(ssum, d);
    float att = p / ssum;

    const unsigned short* colp = xwb + 4 * hl;   // this lane's column slice

    float a0 = 0.f, a1 = 0.f, a2 = 0.f, a3 = 0.f;
    uint2 cur[8], nxt[8];

    #pragma unroll
    for (int i = 0; i < 8; ++i) {
        int j = __shfl(idx, srcb + i);
        cur[i] = *(const uint2*)(colp + (size_t)j * D_OUT);
    }
    #pragma unroll
    for (int b = 0; b < 4; ++b) {
        if (b < 3) {
            #pragma unroll
            for (int i = 0; i < 8; ++i) {
                int j = __shfl(idx, srcb + (b + 1) * 8 + i);
                nxt[i] = *(const uint2*)(colp + (size_t)j * D_OUT);
            }
        }
        #pragma unroll
        for (int i = 0; i < 8; ++i) {
            float w = __shfl(att, srcb + b * 8 + i);
            uint2 v = cur[i];
            a0 = fmaf(w, bflo(v.x), a0);
            a1 = fmaf(w, bfhi(v.x), a1);
            a2 = fmaf(w, bflo(v.y), a2);
            a3 = fmaf(w, bfhi(v.y), a3);
        }
        #pragma unroll
        for (int i = 0; i < 8; ++i) cur[i] = nxt[i];
    }

    float4 o;
    o.x = elu_f(a0);
    o.y = elu_f(a1);
    o.z = elu_f(a2);
    o.w = elu_f(a3);
    *(float4*)(out + (size_t)node * (2 * D_OUT) + D_OUT + 4 * hl) = o;
}

extern "C" void kernel_launch(void* const* d_in, const int* in_sizes, int n_in,
                              void* d_out, int out_size, void* d_ws, size_t ws_size,
                              hipStream_t stream) {
    const float* x     = (const float*)d_in[0];
    const int*   neibs = (const int*)  d_in[1];
    const float* W     = (const float*)d_in[2];
    const float* a     = (const float*)d_in[3];
    float* out = (float*)d_out;

    unsigned short* xwb = (unsigned short*)d_ws;              // N*128 bf16 = 12.8 MB
    float* s_self = (float*)(xwb + (size_t)N_NODES * D_OUT);  // N floats
    float* s_neib = s_self + N_NODES;                         // N floats
    unsigned short* Wp = (unsigned short*)(s_neib + N_NODES); // 256*128 bf16 = 64 KB

    pack_w_kernel<<<128, 256, 0, stream>>>(W, Wp);
    gemm_score_kernel<<<(N_NODES + 63) / 64, 256, 0, stream>>>(
        x, Wp, a, xwb, s_self, s_neib, out);
    // 2 nodes/wave, 4 waves/block -> 8 nodes/block
    aggregate_kernel<<<(N_NODES + 7) / 8, 256, 0, stream>>>(
        neibs, xwb, s_self, s_neib, out);
}

// Round 5
// 154.141 us; speedup vs baseline: 1.0630x; 1.0603x over previous
//
#include <hip/hip_runtime.h>
#include <math.h>

#define N_NODES 50000
#define S_NEIB 32
#define D_IN 256
#define D_OUT 128
#define ALPHA 0.2f

typedef __attribute__((ext_vector_type(8))) short bf16x8;   // 8 bf16 = 4 VGPRs
typedef __attribute__((ext_vector_type(4))) float f32x4;    // MFMA C/D

__device__ __forceinline__ float elu_f(float v) {
    return v > 0.f ? v : (expf(v) - 1.f);
}

// fp32 -> bf16 round-to-nearest-even
__device__ __forceinline__ unsigned short f2bf(float f) {
    unsigned u = __builtin_bit_cast(unsigned, f);
    u += 0x7fffu + ((u >> 16) & 1u);
    return (unsigned short)(u >> 16);
}

// Kernel 0: pack W (256x128 fp32, row-major) into bf16 MFMA B-fragment order:
// Wp[((c*32 + kb)*16 + t)*8 + j] = bf16(W[kb*8+j][c*16+t]),  c=n>>4, kb=k>>3.
__global__ __launch_bounds__(256) void pack_w_kernel(
    const float* __restrict__ W, unsigned short* __restrict__ Wp)
{
    int tid = blockIdx.x * 256 + threadIdx.x;        // 0..32767
    int j  = tid & 7;
    int t  = (tid >> 3) & 15;
    int kb = (tid >> 7) & 31;
    int c  = tid >> 12;
    Wp[tid] = f2bf(W[(kb * 8 + j) * D_OUT + c * 16 + t]);
}

// Kernel 1 (bf16 MFMA): s_self/s_neib = (x@W)@a halves; out[:, :128] = elu(x@W);
// xq = int8 row-scaled quantization of x@W (gather table for kernel 2 —
// halves the 8-XCD compulsory L2-fill traffic vs bf16: gather is past-L2-BW-bound).
__global__ __launch_bounds__(256) void gemm_score_kernel(
    const float* __restrict__ x, const unsigned short* __restrict__ Wp,
    const float* __restrict__ a, signed char* __restrict__ xq,
    float* __restrict__ rowscale,
    float* __restrict__ s_self, float* __restrict__ s_neib,
    float* __restrict__ out)
{
    __shared__ unsigned short xs[64 * 264];  // 33 KB bf16 x-tile (stride 264: 2-way, free)
    __shared__ float ps[2][4][64];
    __shared__ float psm[4][64];
    __shared__ float invs[64];

    const int tid  = threadIdx.x;
    const int lane = tid & 63;
    const int wave = tid >> 6;
    const int q    = lane >> 4;     // quad 0..3
    const int t    = lane & 15;
    const int colW = wave * 32;
    const int r0   = blockIdx.x * 64;

    // stage x tile 64x256 fp32 -> bf16 LDS
    for (int i = 0; i < 16; ++i) {
        int f4  = i * 256 + tid;
        int row = f4 >> 6;
        int c4  = (f4 & 63) << 2;
        float4 v = make_float4(0.f, 0.f, 0.f, 0.f);
        if (r0 + row < N_NODES)
            v = *(const float4*)(x + (size_t)(r0 + row) * D_IN + c4);
        ushort4 b;
        b.x = f2bf(v.x); b.y = f2bf(v.y); b.z = f2bf(v.z); b.w = f2bf(v.w);
        *(ushort4*)&xs[row * 264 + c4] = b;
    }
    __syncthreads();

    const bf16x8* Wp8 = (const bf16x8*)Wp;

    f32x4 acc[4][2];
    #pragma unroll
    for (int mt = 0; mt < 4; ++mt)
        #pragma unroll
        for (int nt = 0; nt < 2; ++nt)
            acc[mt][nt] = (f32x4){0.f, 0.f, 0.f, 0.f};

    #pragma unroll
    for (int kc = 0; kc < 8; ++kc) {
        const int k0 = kc * 32 + q * 8;
        bf16x8 afrag[4];
        #pragma unroll
        for (int mt = 0; mt < 4; ++mt)
            afrag[mt] = *(const bf16x8*)&xs[(mt * 16 + t) * 264 + k0];
        bf16x8 bfrag[2];
        #pragma unroll
        for (int nt = 0; nt < 2; ++nt)
            bfrag[nt] = Wp8[((wave * 2 + nt) * 32 + kc * 4 + q) * 16 + t];
        #pragma unroll
        for (int mt = 0; mt < 4; ++mt)
            #pragma unroll
            for (int nt = 0; nt < 2; ++nt)
                acc[mt][nt] = __builtin_amdgcn_mfma_f32_16x16x32_bf16(
                    afrag[mt], bfrag[nt], acc[mt][nt], 0, 0, 0);
    }

    // score partials + per-row absmax. Lane holds D[row=mt*16+q*4+r][col=colW+nt*16+t];
    // xor d=8..1 reduces over t (bits 0-3), q bits untouched.
    const float as0 = a[colW + t],         as1 = a[colW + 16 + t];
    const float an0 = a[D_OUT + colW + t], an1 = a[D_OUT + colW + 16 + t];
    #pragma unroll
    for (int mt = 0; mt < 4; ++mt) {
        #pragma unroll
        for (int r = 0; r < 4; ++r) {
            float vs = acc[mt][0][r] * as0 + acc[mt][1][r] * as1;
            float vn = acc[mt][0][r] * an0 + acc[mt][1][r] * an1;
            float mv = fmaxf(fabsf(acc[mt][0][r]), fabsf(acc[mt][1][r]));
            #pragma unroll
            for (int d = 8; d >= 1; d >>= 1) {
                vs += __shfl_xor(vs, d);
                vn += __shfl_xor(vn, d);
                mv = fmaxf(mv, __shfl_xor(mv, d));
            }
            if (t == 0) {
                int row = mt * 16 + q * 4 + r;
                ps[0][wave][row] = vs;
                ps[1][wave][row] = vn;
                psm[wave][row]   = mv;
            }
        }
    }
    __syncthreads();
    if (tid < 64) {
        float rm = fmaxf(fmaxf(psm[0][tid], psm[1][tid]),
                         fmaxf(psm[2][tid], psm[3][tid]));
        rm = fmaxf(rm, 1e-20f);
        invs[tid] = 127.f / rm;
        if (r0 + tid < N_NODES) {
            rowscale[r0 + tid] = rm * (1.f / 127.f);
            s_self[r0 + tid] = ps[0][0][tid] + ps[0][1][tid] + ps[0][2][tid] + ps[0][3][tid];
            s_neib[r0 + tid] = ps[1][0][tid] + ps[1][1][tid] + ps[1][2][tid] + ps[1][3][tid];
        }
    }
    __syncthreads();

    // stores: elu(xw) fp32 first half + int8 row-scaled table
    #pragma unroll
    for (int mt = 0; mt < 4; ++mt) {
        #pragma unroll
        for (int r = 0; r < 4; ++r) {
            int row = mt * 16 + q * 4 + r;
            int g   = r0 + row;
            if (g < N_NODES) {
                float inv = invs[row];
                #pragma unroll
                for (int nt = 0; nt < 2; ++nt) {
                    int col = colW + nt * 16 + t;
                    float v = acc[mt][nt][r];
                    out[(size_t)g * (2 * D_OUT) + col] = elu_f(v);
                    float qf = fminf(fmaxf(rintf(v * inv), -127.f), 127.f);
                    xq[(size_t)g * D_OUT + col] = (signed char)(int)qf;
                }
            }
        }
    }
}

// Kernel 2: softmax attention + aggregate over int8 row-scaled table.
// 2 nodes/wave (lanes 0-31 node n0, 32-63 node n0+1); lane owns 4 cols of its
// node -> 1 dword gather per edge (128 B/row). Dequant scale folded into the
// broadcast attention weight (wj = att * rowscale[j]) — zero inner-loop cost.
__global__ __launch_bounds__(256, 4) void aggregate_kernel(
    const int* __restrict__ neibs, const signed char* __restrict__ xq,
    const float* __restrict__ rowscale,
    const float* __restrict__ s_self, const float* __restrict__ s_neib,
    float* __restrict__ out)
{
    const int lane  = threadIdx.x & 63;
    const int wavei = threadIdx.x >> 6;
    const int n0 = (blockIdx.x * 4 + wavei) * 2;
    if (n0 >= N_NODES) return;

    const int half = lane >> 5;
    const int hl   = lane & 31;
    const int node = n0 + half;         // N even -> always < N_NODES
    const int srcb = lane & 32;

    int   idx = neibs[n0 * S_NEIB + lane];   // 64 lanes = both nodes' edges
    float e   = s_self[node] + s_neib[idx];
    e = e > 0.f ? e : ALPHA * e;             // LeakyReLU

    float m = e;
    #pragma unroll
    for (int d = 16; d >= 1; d >>= 1) m = fmaxf(m, __shfl_xor(m, d));
    float p = __expf(e - m);
    float ssum = p;
    #pragma unroll
    for (int d = 16; d >= 1; d >>= 1) ssum += __shfl_xor(ssum, d);
    float wj = (p / ssum) * rowscale[idx];   // attention weight * dequant scale

    const signed char* colp = xq + 4 * hl;

    float a0 = 0.f, a1 = 0.f, a2 = 0.f, a3 = 0.f;
    unsigned cur[8], nxt[8];

    #pragma unroll
    for (int i = 0; i < 8; ++i) {
        int j = __shfl(idx, srcb + i);
        cur[i] = *(const unsigned*)(colp + (size_t)j * D_OUT);
    }
    #pragma unroll
    for (int b = 0; b < 4; ++b) {
        if (b < 3) {
            #pragma unroll
            for (int i = 0; i < 8; ++i) {
                int j = __shfl(idx, srcb + (b + 1) * 8 + i);
                nxt[i] = *(const unsigned*)(colp + (size_t)j * D_OUT);
            }
        }
        #pragma unroll
        for (int i = 0; i < 8; ++i) {
            float w = __shfl(wj, srcb + b * 8 + i);
            unsigned v = cur[i];
            a0 = fmaf(w, (float)((int)(v << 24) >> 24), a0);
            a1 = fmaf(w, (float)((int)(v << 16) >> 24), a1);
            a2 = fmaf(w, (float)((int)(v <<  8) >> 24), a2);
            a3 = fmaf(w, (float)((int)v >> 24),         a3);
        }
        #pragma unroll
        for (int i = 0; i < 8; ++i) cur[i] = nxt[i];
    }

    float4 o;
    o.x = elu_f(a0);
    o.y = elu_f(a1);
    o.z = elu_f(a2);
    o.w = elu_f(a3);
    *(float4*)(out + (size_t)node * (2 * D_OUT) + D_OUT + 4 * hl) = o;
}

extern "C" void kernel_launch(void* const* d_in, const int* in_sizes, int n_in,
                              void* d_out, int out_size, void* d_ws, size_t ws_size,
                              hipStream_t stream) {
    const float* x     = (const float*)d_in[0];
    const int*   neibs = (const int*)  d_in[1];
    const float* W     = (const float*)d_in[2];
    const float* a     = (const float*)d_in[3];
    float* out = (float*)d_out;

    signed char* xq    = (signed char*)d_ws;                  // N*128 int8 = 6.4 MB
    float* rowscale    = (float*)(xq + (size_t)N_NODES * D_OUT);
    float* s_self      = rowscale + N_NODES;
    float* s_neib      = s_self + N_NODES;
    unsigned short* Wp = (unsigned short*)(s_neib + N_NODES); // 64 KB

    pack_w_kernel<<<128, 256, 0, stream>>>(W, Wp);
    gemm_score_kernel<<<(N_NODES + 63) / 64, 256, 0, stream>>>(
        x, Wp, a, xq, rowscale, s_self, s_neib, out);
    aggregate_kernel<<<(N_NODES + 7) / 8, 256, 0, stream>>>(
        neibs, xq, rowscale, s_self, s_neib, out);
}